// Round 5
// baseline (66.374 us; speedup 1.0000x reference)
//
#include <hip/hip_runtime.h>
#include <hip/hip_bf16.h>
#include <math.h>

// ThickCubeSimulator R4: 3-kernel split + cheap branchless atan.
//  k1 gtable: Gaussian table GT[M][b] (stride 164, pad-zeroed) + params block.
//  k2 deposit: 2 coarse pixels/block, 256 thr, 16 column-parity sub-hists,
//     ds_add_f32; ~24 VALU + 4 trans per cell (was ~90 w/ ocml atan + div).
//  k3 matvec: out[M,pix] = sum_b H[pix][b]*GT[M][b]; 32 pixels/block,
//     conflict-free padded LDS strides.
// Fallback (ws too small): fused R3-style kernel with the same cheap math.

#define RES   80
#define NB    160
#define NBP   161
#define NM    40
#define GTP   164        // padded row stride (floats) for GT and H
#define NPIXT (RES*RES)
#define C_KMS 299792.458f
#define F0GHZ 230.538f
#define LOG2E 1.44269504088896340736f
#define HPI   1.57079632679489662f
#define VBIN0 -198.75f
#define VBINW 2.5f

// ws layout (bytes)
#define PRM_OFF 0
#define GT_OFF  128
#define H_OFF   32768
#define WS_REQ  (32768 + (size_t)NPIXT * GTP * 4)

__device__ __forceinline__ float fast_exp2(float x) {
#if __has_builtin(__builtin_amdgcn_exp2f)
  return __builtin_amdgcn_exp2f(x);
#else
  return exp2f(x);
#endif
}
__device__ __forceinline__ float fast_rcp(float x) {
#if __has_builtin(__builtin_amdgcn_rcpf)
  return __builtin_amdgcn_rcpf(x);
#else
  return 1.0f / x;
#endif
}

// atan(u) for u>=0 via t=min(u,1/u) in [0,1], poly err ~1e-6 rad
__device__ __forceinline__ float atan_pos(float u, float uinv) {
  const float t  = fminf(u, uinv);
  const float t2 = t * t;
  float p = fmaf(t2, -0.0117212f, 0.05265332f);
  p = fmaf(t2, p, -0.11643287f);
  p = fmaf(t2, p, 0.19354346f);
  p = fmaf(t2, p, -0.33262347f);
  p = fmaf(t2, p, 0.99997726f);
  const float a = t * p;
  return (u <= 1.0f) ? a : (HPI - a);
}

// ---- k1: GT table + params ----
__global__ __launch_bounds__(256) void gtable_kernel(
    const float* __restrict__ p_inc, const float* __restrict__ p_rot,
    const float* __restrict__ p_lb,  const float* __restrict__ p_vs,
    const float* __restrict__ p_vmax, const float* __restrict__ p_rturn,
    const float* __restrict__ p_i0,  const float* __restrict__ p_rd,
    const float* __restrict__ freqs, float* __restrict__ ws)
{
  float* gt  = ws + GT_OFF / 4;
  const int e = blockIdx.x * 256 + threadIdx.x;
  if (e < NM * GTP) {
    const int M = e / GTP;
    const int b = e - M * GTP;
    float val = 0.f;
    if (b < NB) {
      const float sig    = p_lb[0];
      const float vshift = p_vs[0];
      const float fc0    = freqs[0];
      const float fc1    = freqs[1];
      const float c2l    = -0.5f * LOG2E / (sig * sig);
      const float norm16 = 0.3989422804014327f / sig * 0.0625f;
      const float df = (fc1 - fc0) * 0.25f;
      const float f0 = fc0 - 1.5f * df;
      const float vbin = VBIN0 + VBINW * (float)b;
      float s = 0.f;
      #pragma unroll
      for (int r = 0; r < 4; ++r) {
        const float ffine = f0 + df * (float)(4 * M + r);
        const float vlab  = C_KMS * (F0GHZ - ffine) / F0GHZ - vshift;
        const float d = vlab - vbin;
        s += fast_exp2(c2l * d * d);
      }
      val = s * norm16;
    }
    gt[e] = val;
  }
  if (blockIdx.x == 0 && threadIdx.x == 0) {
    const float inc = p_inc[0], rot = p_rot[0];
    const float si = sinf(inc);
    float* prm = ws + PRM_OFF / 4;
    prm[0] = cosf(inc);                              // ci
    prm[1] = si;                                     // si
    prm[2] = cosf(rot);                              // cr
    prm[3] = sinf(rot);                              // sr
    prm[4] = -p_vmax[0] * 0.63661977236758134f * si; // kfac
    prm[5] = 1.0f / p_rturn[0];                      // irt
    prm[6] = p_rturn[0];                             // rt
    prm[7] = -LOG2E / p_rd[0];                       // crd
    prm[8] = __log2f(p_i0[0]);                       // li0
    prm[9] = 1.0f / VBINW;                           // invw
    prm[10] = -VBIN0 / VBINW;                        // boff
  }
}

// ---- shared deposit math ----
#define LOAD_PRM(prm) \
  const float ci   = prm[0]; const float si   = prm[1]; \
  const float cr   = prm[2]; const float sr   = prm[3]; \
  const float kfac = prm[4]; const float irt  = prm[5]; \
  const float rt   = prm[6]; const float crd  = prm[7]; \
  const float li0  = prm[8]; const float invw = prm[9]; \
  const float boff = prm[10];

// ---- k2: deposit (2 coarse pixels / block) ----
__global__ __launch_bounds__(256) void deposit_kernel(
    const float* __restrict__ ws_prm, float* __restrict__ h)
{
  __shared__ float Hs[16 * NBP];   // 10304 B
  const int t   = threadIdx.x;
  const int blk = blockIdx.x;           // 0..3199
  const int p   = blk / (RES / 2);
  const int q0  = (blk - p * (RES / 2)) * 2;
  const float* prm = ws_prm;
  LOAD_PRM(prm)

  for (int e = t; e < 16 * NBP; e += 256) Hs[e] = 0.f;
  __syncthreads();

  const int col = t & 7;     // 0..7 = pixel v(0..1) x fine 2x2
  const int zb  = t >> 3;    // 0..31
  const int v   = col >> 2;
  const int fp  = col & 3;
  const int i   = 2 * p + (fp >> 1);
  const int j   = 2 * (q0 + v) + (fp & 1);
  const float gx = -993.75f + 12.5f * (float)i;
  const float gy = -993.75f + 12.5f * (float)j;
  const float x1 = gx * cr - gy * sr;
  const float y1 = gx * sr + gy * cr;
  const float x12  = x1 * x1;
  const float gxy2 = gx * gx + gy * gy;
  const float y1ci = y1 * ci;
  const float kcol = kfac * x1;
  float* Hc = &Hs[(col * 2 + (zb & 1)) * NBP];

  #pragma unroll
  for (int it = 0; it < 5; ++it) {
    const int k = zb * 5 + it;            // bijective over 0..159
    const float gz = -993.75f + 12.5f * (float)k;
    const float ry   = fmaf(-si, gz, y1ci);
    const float rcyl = sqrtf(fmaf(ry, ry, x12));
    const float rinv = fast_rcp(fmaxf(rcyl, 1e-30f));
    const float u    = rcyl * irt;
    const float at   = atan_pos(u, rt * rinv);
    const float vlos = kcol * (rinv * at);
    const float rsph = sqrtf(fmaf(gz, gz, gxy2));
    const float inten = fast_exp2(fmaf(rsph, crd, li0));
    const float uu = fmaf(vlos, invw, boff);   // in (1.2, 157.8): no clamp
    const float bf = floorf(uu);
    const int   bi = (int)bf;
    const float w1 = inten * (uu - bf);
    unsafeAtomicAdd(&Hc[bi],     inten - w1);
    unsafeAtomicAdd(&Hc[bi + 1], w1);
  }
  __syncthreads();

  // reduce 16 sub-hists -> 2 pixel rows (pad-zeroed), coalesced global write
  for (int e = t; e < 2 * GTP; e += 256) {
    const int v2 = e / GTP;
    const int bb = e - v2 * GTP;
    float s = 0.f;
    if (bb < NB) {
      #pragma unroll
      for (int c8 = 0; c8 < 8; ++c8) s += Hs[(v2 * 8 + c8) * NBP + bb];
    }
    h[(size_t)(p * RES + q0 + v2) * GTP + bb] = s;
  }
}

// ---- k3: matvec out[M,pix] = sum_b H[pix][b]*GT[M][b] ----
__global__ __launch_bounds__(256) void matvec_kernel(
    const float* __restrict__ gt, const float* __restrict__ h,
    float* __restrict__ out)
{
  __shared__ __align__(16) float GTl[NM * GTP];   // 26240 B
  __shared__ __align__(16) float Hl[32 * GTP];    // 20992 B
  const int t    = threadIdx.x;
  const int pix0 = blockIdx.x * 32;

  for (int e = t; e < NM * GTP / 4; e += 256)
    ((float4*)GTl)[e] = ((const float4*)gt)[e];
  const float4* hsrc = (const float4*)(h + (size_t)pix0 * GTP);
  for (int e = t; e < 32 * GTP / 4; e += 256)
    ((float4*)Hl)[e] = hsrc[e];
  __syncthreads();

  const int pix = t >> 3;        // 0..31
  const int Mb  = (t & 7) * 5;   // 5 channels per thread
  const float4* Hp = (const float4*)&Hl[pix * GTP];
  float a0 = 0.f, a1 = 0.f, a2 = 0.f, a3 = 0.f, a4 = 0.f;
  for (int c = 0; c < GTP / 4; ++c) {   // 41 chunks (pads are zero)
    const float4 h4 = Hp[c];
    const float4 g0 = ((const float4*)&GTl[(Mb + 0) * GTP])[c];
    const float4 g1 = ((const float4*)&GTl[(Mb + 1) * GTP])[c];
    const float4 g2 = ((const float4*)&GTl[(Mb + 2) * GTP])[c];
    const float4 g3 = ((const float4*)&GTl[(Mb + 3) * GTP])[c];
    const float4 g4 = ((const float4*)&GTl[(Mb + 4) * GTP])[c];
    a0 = fmaf(h4.x, g0.x, fmaf(h4.y, g0.y, fmaf(h4.z, g0.z, fmaf(h4.w, g0.w, a0))));
    a1 = fmaf(h4.x, g1.x, fmaf(h4.y, g1.y, fmaf(h4.z, g1.z, fmaf(h4.w, g1.w, a1))));
    a2 = fmaf(h4.x, g2.x, fmaf(h4.y, g2.y, fmaf(h4.z, g2.z, fmaf(h4.w, g2.w, a2))));
    a3 = fmaf(h4.x, g3.x, fmaf(h4.y, g3.y, fmaf(h4.z, g3.z, fmaf(h4.w, g3.w, a3))));
    a4 = fmaf(h4.x, g4.x, fmaf(h4.y, g4.y, fmaf(h4.z, g4.z, fmaf(h4.w, g4.w, a4))));
  }
  const int pixid = pix0 + pix;
  out[(size_t)(Mb + 0) * NPIXT + pixid] = a0;
  out[(size_t)(Mb + 1) * NPIXT + pixid] = a1;
  out[(size_t)(Mb + 2) * NPIXT + pixid] = a2;
  out[(size_t)(Mb + 3) * NPIXT + pixid] = a3;
  out[(size_t)(Mb + 4) * NPIXT + pixid] = a4;
}

// ---- fallback: fused (R3 structure + cheap math), used if ws too small ----
__global__ __launch_bounds__(512) void fused_kernel(
    const float* __restrict__ ws_prm, const float* __restrict__ gt,
    float* __restrict__ out)
{
  __shared__ __align__(16) float GT[NM * GTP];
  __shared__ float H16[16 * NBP];
  __shared__ __align__(16) float H4[4 * GTP];
  const int t   = threadIdx.x;
  const int blk = blockIdx.x;
  const int p   = blk / (RES / 4);
  const int q0  = (blk - p * (RES / 4)) * 4;
  const float* prm = ws_prm;
  LOAD_PRM(prm)

  for (int e = t; e < NM * GTP / 4; e += 512)
    ((float4*)GT)[e] = ((const float4*)gt)[e];
  for (int e = t; e < 16 * NBP; e += 512) H16[e] = 0.f;
  __syncthreads();

  {
    const int col = t & 15;
    const int zb  = t >> 4;
    const int v   = col >> 2;
    const int fp  = col & 3;
    const int i   = 2 * p + (fp >> 1);
    const int j   = 2 * (q0 + v) + (fp & 1);
    const float gx = -993.75f + 12.5f * (float)i;
    const float gy = -993.75f + 12.5f * (float)j;
    const float x1 = gx * cr - gy * sr;
    const float y1 = gx * sr + gy * cr;
    const float x12  = x1 * x1;
    const float gxy2 = gx * gx + gy * gy;
    const float y1ci = y1 * ci;
    const float kcol = kfac * x1;
    float* Hc = &H16[col * NBP];
    #pragma unroll
    for (int it = 0; it < 5; ++it) {
      const int k = zb * 5 + it;
      const float gz = -993.75f + 12.5f * (float)k;
      const float ry   = fmaf(-si, gz, y1ci);
      const float rcyl = sqrtf(fmaf(ry, ry, x12));
      const float rinv = fast_rcp(fmaxf(rcyl, 1e-30f));
      const float u    = rcyl * irt;
      const float at   = atan_pos(u, rt * rinv);
      const float vlos = kcol * (rinv * at);
      const float rsph = sqrtf(fmaf(gz, gz, gxy2));
      const float inten = fast_exp2(fmaf(rsph, crd, li0));
      const float uu = fmaf(vlos, invw, boff);
      const float bf = floorf(uu);
      const int   bi = (int)bf;
      const float w1 = inten * (uu - bf);
      unsafeAtomicAdd(&Hc[bi],     inten - w1);
      unsafeAtomicAdd(&Hc[bi + 1], w1);
    }
  }
  __syncthreads();

  for (int e = t; e < 4 * NB; e += 512) {
    const int v = e / NB;
    const int b = e - v * NB;
    H4[v * GTP + b] = (H16[(4 * v + 0) * NBP + b] + H16[(4 * v + 1) * NBP + b])
                    + (H16[(4 * v + 2) * NBP + b] + H16[(4 * v + 3) * NBP + b]);
  }
  __syncthreads();

  if (t < 4 * NM) {
    const int M = t >> 2;
    const int v = t & 3;
    const float4* Hv = (const float4*)&H4[v * GTP];
    const float4* Gm = (const float4*)&GT[M * GTP];
    float acc = 0.f;
    #pragma unroll 10
    for (int c = 0; c < NB / 4; ++c) {
      const float4 hh = Hv[c];
      const float4 gg = Gm[c];
      acc = fmaf(hh.x, gg.x, fmaf(hh.y, gg.y, fmaf(hh.z, gg.z, fmaf(hh.w, gg.w, acc))));
    }
    out[(size_t)M * NPIXT + p * RES + (q0 + v)] = acc;
  }
}

extern "C" void kernel_launch(void* const* d_in, const int* in_sizes, int n_in,
                              void* d_out, int out_size, void* d_ws, size_t ws_size,
                              hipStream_t stream) {
  const float* p_inc   = (const float*)d_in[0];
  const float* p_rot   = (const float*)d_in[1];
  const float* p_lb    = (const float*)d_in[2];
  const float* p_vs    = (const float*)d_in[3];
  const float* p_vmax  = (const float*)d_in[4];
  const float* p_rturn = (const float*)d_in[5];
  const float* p_i0    = (const float*)d_in[6];
  const float* p_rd    = (const float*)d_in[7];
  const float* freqs   = (const float*)d_in[8];
  float* out = (float*)d_out;
  float* ws  = (float*)d_ws;
  float* prm = ws + PRM_OFF / 4;
  float* gt  = ws + GT_OFF / 4;
  float* h   = (float*)((char*)d_ws + H_OFF);

  hipLaunchKernelGGL(gtable_kernel, dim3((NM * GTP + 255) / 256), dim3(256),
                     0, stream, p_inc, p_rot, p_lb, p_vs, p_vmax, p_rturn,
                     p_i0, p_rd, freqs, ws);
  if (ws_size >= WS_REQ) {
    hipLaunchKernelGGL(deposit_kernel, dim3(RES * (RES / 2)), dim3(256),
                       0, stream, prm, h);
    hipLaunchKernelGGL(matvec_kernel, dim3(NPIXT / 32), dim3(256),
                       0, stream, gt, h, out);
  } else {
    hipLaunchKernelGGL(fused_kernel, dim3(RES * (RES / 4)), dim3(512),
                       0, stream, prm, gt, out);
  }
}

// Round 6
// 45.085 us; speedup vs baseline: 1.4722x; 1.4722x over previous
//
#include <hip/hip_runtime.h>
#include <hip/hip_bf16.h>
#include <math.h>

// ThickCubeSimulator R5: atomic-COUNT reduction via run-length-merged CIC.
//  Evidence (R2-R4): LDS f32 atomics cost ~3.4 CU-cyc per LANE regardless of
//  conflict layout -> 8.19M lane-atomics ~= 45us was the deposit floor.
//  R5 deposit: thread owns 10 CONSECUTIVE z (vlos smooth in z), keeps the CIC
//  pair (cb, a0, a1) in registers, flushes on bin change; +1 steps flush ONE
//  atomic (a1 folds into next a0). Expected ~0.7-1 atomics/cell (was 2).
//  Matvec: 1067 blocks (6 pix x 40 M), GT in LDS, H streamed from L2/L3.

#define RES   80
#define NB    160
#define NBP   161
#define NM    40
#define GTP   164        // padded row stride (floats) for GT and H
#define NPIXT (RES*RES)
#define NPIXB 4          // pixels per deposit block
#define NSH   8          // sub-hists per pixel
#define C_KMS 299792.458f
#define F0GHZ 230.538f
#define LOG2E 1.44269504088896340736f
#define HPI   1.57079632679489662f
#define VBIN0 -198.75f
#define VBINW 2.5f

// ws layout (bytes)
#define PRM_OFF 0
#define GT_OFF  128
#define H_OFF   32768
#define WS_REQ  (32768 + (size_t)NPIXT * GTP * 4)

__device__ __forceinline__ float fast_exp2(float x) {
#if __has_builtin(__builtin_amdgcn_exp2f)
  return __builtin_amdgcn_exp2f(x);
#else
  return exp2f(x);
#endif
}
__device__ __forceinline__ float fast_rcp(float x) {
#if __has_builtin(__builtin_amdgcn_rcpf)
  return __builtin_amdgcn_rcpf(x);
#else
  return 1.0f / x;
#endif
}

// atan(u) for u>=0 via t=min(u,1/u) in [0,1], poly err ~1e-6 rad
__device__ __forceinline__ float atan_pos(float u, float uinv) {
  const float t  = fminf(u, uinv);
  const float t2 = t * t;
  float p = fmaf(t2, -0.0117212f, 0.05265332f);
  p = fmaf(t2, p, -0.11643287f);
  p = fmaf(t2, p, 0.19354346f);
  p = fmaf(t2, p, -0.33262347f);
  p = fmaf(t2, p, 0.99997726f);
  const float a = t * p;
  return (u <= 1.0f) ? a : (HPI - a);
}

// ---- k1: GT table + params ----
__global__ __launch_bounds__(256) void gtable_kernel(
    const float* __restrict__ p_inc, const float* __restrict__ p_rot,
    const float* __restrict__ p_lb,  const float* __restrict__ p_vs,
    const float* __restrict__ p_vmax, const float* __restrict__ p_rturn,
    const float* __restrict__ p_i0,  const float* __restrict__ p_rd,
    const float* __restrict__ freqs, float* __restrict__ ws)
{
  float* gt  = ws + GT_OFF / 4;
  const int e = blockIdx.x * 256 + threadIdx.x;
  if (e < NM * GTP) {
    const int M = e / GTP;
    const int b = e - M * GTP;
    float val = 0.f;
    if (b < NB) {
      const float sig    = p_lb[0];
      const float vshift = p_vs[0];
      const float fc0    = freqs[0];
      const float fc1    = freqs[1];
      const float c2l    = -0.5f * LOG2E / (sig * sig);
      const float norm16 = 0.3989422804014327f / sig * 0.0625f;
      const float df = (fc1 - fc0) * 0.25f;
      const float f0 = fc0 - 1.5f * df;
      const float vbin = VBIN0 + VBINW * (float)b;
      float s = 0.f;
      #pragma unroll
      for (int r = 0; r < 4; ++r) {
        const float ffine = f0 + df * (float)(4 * M + r);
        const float vlab  = C_KMS * (F0GHZ - ffine) / F0GHZ - vshift;
        const float d = vlab - vbin;
        s += fast_exp2(c2l * d * d);
      }
      val = s * norm16;
    }
    gt[e] = val;
  }
  if (blockIdx.x == 0 && threadIdx.x == 0) {
    const float inc = p_inc[0], rot = p_rot[0];
    const float si = sinf(inc);
    float* prm = ws + PRM_OFF / 4;
    prm[0] = cosf(inc);                              // ci
    prm[1] = si;                                     // si
    prm[2] = cosf(rot);                              // cr
    prm[3] = sinf(rot);                              // sr
    prm[4] = -p_vmax[0] * 0.63661977236758134f * si; // kfac
    prm[5] = 1.0f / p_rturn[0];                      // irt
    prm[6] = p_rturn[0];                             // rt
    prm[7] = -LOG2E / p_rd[0];                       // crd
    prm[8] = __log2f(p_i0[0]);                       // li0
    prm[9] = 1.0f / VBINW;                           // invw
    prm[10] = -VBIN0 / VBINW;                        // boff
  }
}

#define LOAD_PRM(prm) \
  const float ci   = prm[0]; const float si   = prm[1]; \
  const float cr   = prm[2]; const float sr   = prm[3]; \
  const float kfac = prm[4]; const float irt  = prm[5]; \
  const float rt   = prm[6]; const float crd  = prm[7]; \
  const float li0  = prm[8]; const float invw = prm[9]; \
  const float boff = prm[10];

// per-cell math: produces bi, w0, w1
#define CELL_MATH(k)                                             \
    const float gz = -993.75f + 12.5f * (float)(k);              \
    const float ry   = fmaf(-si, gz, y1ci);                      \
    const float rcyl = sqrtf(fmaf(ry, ry, x12));                 \
    const float rinv = fast_rcp(fmaxf(rcyl, 1e-30f));            \
    const float u    = rcyl * irt;                               \
    const float at   = atan_pos(u, rt * rinv);                   \
    const float vlos = kcol * (rinv * at);                       \
    const float rsph = sqrtf(fmaf(gz, gz, gxy2));                \
    const float inten = fast_exp2(fmaf(rsph, crd, li0));         \
    const float uu = fmaf(vlos, invw, boff);  /* in (1.2,157.8) */ \
    const int   bi = (int)uu;                                    \
    const float w1 = inten * (uu - (float)bi);                   \
    const float w0 = inten - w1;

// ---- k2: deposit (4 coarse pixels / block; wave = pixel; 10 z per thread) ----
__global__ __launch_bounds__(256) void deposit_kernel(
    const float* __restrict__ ws_prm, float* __restrict__ h)
{
  __shared__ float Hs[NPIXB * NSH * NBP];   // 4*8*161*4 = 20608 B
  const int t   = threadIdx.x;
  const int blk = blockIdx.x;                  // 0..1599
  const int p   = blk / (RES / NPIXB);
  const int q0  = (blk - p * (RES / NPIXB)) * NPIXB;
  const float* prm = ws_prm;
  LOAD_PRM(prm)

  for (int e = t; e < NPIXB * NSH * NBP; e += 256) Hs[e] = 0.f;
  __syncthreads();

  // wave = pixel; col = fine 2x2 pixel; seg = 10-consecutive-z segment
  const int pix = t >> 6;          // 0..3
  const int col = (t >> 4) & 3;    // 0..3
  const int seg = t & 15;          // 0..15 -> z in [seg*10, seg*10+10)
  const int i   = 2 * p + (col >> 1);
  const int j   = 2 * (q0 + pix) + (col & 1);
  const float gx = -993.75f + 12.5f * (float)i;
  const float gy = -993.75f + 12.5f * (float)j;
  const float x1 = gx * cr - gy * sr;
  const float y1 = gx * sr + gy * cr;
  const float x12  = x1 * x1;
  const float gxy2 = gx * gx + gy * gy;
  const float y1ci = y1 * ci;
  const float kcol = kfac * x1;
  float* Hc = &Hs[(pix * NSH + col * 2 + (seg & 1)) * NBP];

  const int k0 = seg * 10;
  int   cb;  float a0, a1;
  {                                   // peel first cell
    CELL_MATH(k0)
    cb = bi; a0 = w0; a1 = w1;
  }
  #pragma unroll
  for (int it = 1; it < 10; ++it) {
    CELL_MATH(k0 + it)
    if (bi == cb) {                   // same bin pair: pure register merge
      a0 += w0; a1 += w1;
    } else if (bi == cb + 1) {        // +1 step: one atomic, carry a1 forward
      unsafeAtomicAdd(&Hc[cb], a0);
      a0 = a1 + w0; a1 = w1; cb = bi;
    } else {                          // jump: full flush
      unsafeAtomicAdd(&Hc[cb],     a0);
      unsafeAtomicAdd(&Hc[cb + 1], a1);
      a0 = w0; a1 = w1; cb = bi;
    }
  }
  unsafeAtomicAdd(&Hc[cb],     a0);   // final flush
  unsafeAtomicAdd(&Hc[cb + 1], a1);
  __syncthreads();

  // reduce NSH sub-hists -> per-pixel row (pad-zeroed), coalesced global write
  for (int e = t; e < NPIXB * GTP; e += 256) {
    const int v  = e / GTP;
    const int bb = e - v * GTP;
    float s = 0.f;
    if (bb < NB) {
      #pragma unroll
      for (int c8 = 0; c8 < NSH; ++c8) s += Hs[(v * NSH + c8) * NBP + bb];
    }
    h[(size_t)(p * RES + q0 + v) * GTP + bb] = s;
  }
}

// ---- k3: matvec out[M,pix] = sum_b H[pix][b]*GT[M][b] ----
// 240 of 256 threads: t = M*6 + pix (6 pixels, 40 channels). 1067 blocks.
__global__ __launch_bounds__(256) void matvec_kernel(
    const float* __restrict__ gt, const float* __restrict__ h,
    float* __restrict__ out)
{
  __shared__ __align__(16) float GTl[NM * GTP];   // 26240 B
  const int t    = threadIdx.x;
  const int pix0 = blockIdx.x * 6;

  for (int e = t; e < NM * GTP / 4; e += 256)
    ((float4*)GTl)[e] = ((const float4*)gt)[e];
  __syncthreads();

  if (t >= 240) return;
  const int M   = t / 6;
  const int pix = t - M * 6;
  const int pixid = pix0 + pix;
  if (pixid >= NPIXT) return;

  const float4* Hp = (const float4*)(h + (size_t)pixid * GTP);
  const float4* Gm = (const float4*)&GTl[M * GTP];
  float acc = 0.f;
  #pragma unroll 8
  for (int c = 0; c < NB / 4; ++c) {
    const float4 hh = Hp[c];
    const float4 gg = Gm[c];
    acc = fmaf(hh.x, gg.x, fmaf(hh.y, gg.y, fmaf(hh.z, gg.z, fmaf(hh.w, gg.w, acc))));
  }
  out[(size_t)M * NPIXT + pixid] = acc;
}

// ---- fallback: fused (R4 structure), used only if ws too small ----
__global__ __launch_bounds__(512) void fused_kernel(
    const float* __restrict__ ws_prm, const float* __restrict__ gt,
    float* __restrict__ out)
{
  __shared__ __align__(16) float GT[NM * GTP];
  __shared__ float H16[16 * NBP];
  __shared__ __align__(16) float H4[4 * GTP];
  const int t   = threadIdx.x;
  const int blk = blockIdx.x;
  const int p   = blk / (RES / 4);
  const int q0  = (blk - p * (RES / 4)) * 4;
  const float* prm = ws_prm;
  LOAD_PRM(prm)

  for (int e = t; e < NM * GTP / 4; e += 512)
    ((float4*)GT)[e] = ((const float4*)gt)[e];
  for (int e = t; e < 16 * NBP; e += 512) H16[e] = 0.f;
  __syncthreads();

  {
    const int col = t & 15;
    const int zb  = t >> 4;
    const int v   = col >> 2;
    const int fp  = col & 3;
    const int i   = 2 * p + (fp >> 1);
    const int j   = 2 * (q0 + v) + (fp & 1);
    const float gx = -993.75f + 12.5f * (float)i;
    const float gy = -993.75f + 12.5f * (float)j;
    const float x1 = gx * cr - gy * sr;
    const float y1 = gx * sr + gy * cr;
    const float x12  = x1 * x1;
    const float gxy2 = gx * gx + gy * gy;
    const float y1ci = y1 * ci;
    const float kcol = kfac * x1;
    float* Hc = &H16[col * NBP];
    #pragma unroll
    for (int it = 0; it < 5; ++it) {
      const int k = zb * 5 + it;
      CELL_MATH(k)
      unsafeAtomicAdd(&Hc[bi],     w0);
      unsafeAtomicAdd(&Hc[bi + 1], w1);
    }
  }
  __syncthreads();

  for (int e = t; e < 4 * NB; e += 512) {
    const int v = e / NB;
    const int b = e - v * NB;
    H4[v * GTP + b] = (H16[(4 * v + 0) * NBP + b] + H16[(4 * v + 1) * NBP + b])
                    + (H16[(4 * v + 2) * NBP + b] + H16[(4 * v + 3) * NBP + b]);
  }
  __syncthreads();

  if (t < 4 * NM) {
    const int M = t >> 2;
    const int v = t & 3;
    const float4* Hv = (const float4*)&H4[v * GTP];
    const float4* Gm = (const float4*)&GT[M * GTP];
    float acc = 0.f;
    #pragma unroll 10
    for (int c = 0; c < NB / 4; ++c) {
      const float4 hh = Hv[c];
      const float4 gg = Gm[c];
      acc = fmaf(hh.x, gg.x, fmaf(hh.y, gg.y, fmaf(hh.z, gg.z, fmaf(hh.w, gg.w, acc))));
    }
    out[(size_t)M * NPIXT + p * RES + (q0 + v)] = acc;
  }
}

extern "C" void kernel_launch(void* const* d_in, const int* in_sizes, int n_in,
                              void* d_out, int out_size, void* d_ws, size_t ws_size,
                              hipStream_t stream) {
  const float* p_inc   = (const float*)d_in[0];
  const float* p_rot   = (const float*)d_in[1];
  const float* p_lb    = (const float*)d_in[2];
  const float* p_vs    = (const float*)d_in[3];
  const float* p_vmax  = (const float*)d_in[4];
  const float* p_rturn = (const float*)d_in[5];
  const float* p_i0    = (const float*)d_in[6];
  const float* p_rd    = (const float*)d_in[7];
  const float* freqs   = (const float*)d_in[8];
  float* out = (float*)d_out;
  float* ws  = (float*)d_ws;
  float* prm = ws + PRM_OFF / 4;
  float* gt  = ws + GT_OFF / 4;
  float* h   = (float*)((char*)d_ws + H_OFF);

  hipLaunchKernelGGL(gtable_kernel, dim3((NM * GTP + 255) / 256), dim3(256),
                     0, stream, p_inc, p_rot, p_lb, p_vs, p_vmax, p_rturn,
                     p_i0, p_rd, freqs, ws);
  if (ws_size >= WS_REQ) {
    hipLaunchKernelGGL(deposit_kernel, dim3(NPIXT / NPIXB), dim3(256),
                       0, stream, prm, h);
    hipLaunchKernelGGL(matvec_kernel, dim3((NPIXT + 5) / 6), dim3(256),
                       0, stream, gt, h, out);
  } else {
    hipLaunchKernelGGL(fused_kernel, dim3(RES * (RES / 4)), dim3(512),
                       0, stream, prm, gt, out);
  }
}

// Round 7
// 31.822 us; speedup vs baseline: 2.0858x; 1.4168x over previous
//
#include <hip/hip_runtime.h>
#include <hip/hip_bf16.h>
#include <math.h>

// ThickCubeSimulator R6: latency-oriented rebuild of the deposit.
//  Evidence: R4 deposit ran at VGPR=12, VALUBusy 16% -> each cell was ONE long
//  dependent chain (~100cy) with zero ILP; R5 added a serial merge dependence.
//  Total deposit VALU work is only ~1.5us at full issue -> latency-bound.
//  R6: (a) batch 5 cells as independent chains (unrolled reg arrays), then a
//  cheap serial merge+flush; (b) fuse the matvec into the deposit kernel
//  (histogram is block-local; GT[b][M] streamed coalesced from L1, H broadcast
//  from LDS) -> 2 kernels total, no H round-trip; (c) 23KB LDS, lb(256,7).

#define RES   80
#define NB    160
#define NBP   161
#define NM    40
#define NPIXT (RES*RES)
#define NPIXB 4          // coarse pixels per block
#define C_KMS 299792.458f
#define F0GHZ 230.538f
#define LOG2E 1.44269504088896340736f
#define HPI   1.57079632679489662f
#define VBIN0 -198.75f
#define VBINW 2.5f

// ws layout (bytes): prm[0..31] floats, then GT[b][M] (NB*NM floats)
#define PRM_OFF 0
#define GT_OFF  128
#define WS_REQ  (GT_OFF + NB * NM * 4)

__device__ __forceinline__ float fast_exp2(float x) {
#if __has_builtin(__builtin_amdgcn_exp2f)
  return __builtin_amdgcn_exp2f(x);
#else
  return exp2f(x);
#endif
}
__device__ __forceinline__ float fast_rcp(float x) {
#if __has_builtin(__builtin_amdgcn_rcpf)
  return __builtin_amdgcn_rcpf(x);
#else
  return 1.0f / x;
#endif
}

// atan(u) for u>=0 via t=min(u,1/u) in [0,1], poly err ~1e-6 rad
__device__ __forceinline__ float atan_pos(float u, float uinv) {
  const float t  = fminf(u, uinv);
  const float t2 = t * t;
  float p = fmaf(t2, -0.0117212f, 0.05265332f);
  p = fmaf(t2, p, -0.11643287f);
  p = fmaf(t2, p, 0.19354346f);
  p = fmaf(t2, p, -0.33262347f);
  p = fmaf(t2, p, 0.99997726f);
  const float a = t * p;
  return (u <= 1.0f) ? a : (HPI - a);
}

// ---- k1: GT table (transposed: GT[b*NM + M]) + params ----
__global__ __launch_bounds__(256) void gtable_kernel(
    const float* __restrict__ p_inc, const float* __restrict__ p_rot,
    const float* __restrict__ p_lb,  const float* __restrict__ p_vs,
    const float* __restrict__ p_vmax, const float* __restrict__ p_rturn,
    const float* __restrict__ p_i0,  const float* __restrict__ p_rd,
    const float* __restrict__ freqs, float* __restrict__ ws)
{
  float* gt = ws + GT_OFF / 4;
  const int e = blockIdx.x * 256 + threadIdx.x;
  if (e < NB * NM) {
    const int b = e / NM;
    const int M = e - b * NM;
    const float sig    = p_lb[0];
    const float vshift = p_vs[0];
    const float fc0    = freqs[0];
    const float fc1    = freqs[1];
    const float c2l    = -0.5f * LOG2E / (sig * sig);
    const float norm16 = 0.3989422804014327f / sig * 0.0625f;
    const float df = (fc1 - fc0) * 0.25f;
    const float f0 = fc0 - 1.5f * df;
    const float vbin = VBIN0 + VBINW * (float)b;
    float s = 0.f;
    #pragma unroll
    for (int r = 0; r < 4; ++r) {
      const float ffine = f0 + df * (float)(4 * M + r);
      const float vlab  = C_KMS * (F0GHZ - ffine) / F0GHZ - vshift;
      const float d = vlab - vbin;
      s += fast_exp2(c2l * d * d);
    }
    gt[e] = s * norm16;
  }
  if (blockIdx.x == 0 && threadIdx.x == 0) {
    const float inc = p_inc[0], rot = p_rot[0];
    const float si = sinf(inc);
    float* prm = ws + PRM_OFF / 4;
    prm[0] = cosf(inc);                              // ci
    prm[1] = si;                                     // si
    prm[2] = cosf(rot);                              // cr
    prm[3] = sinf(rot);                              // sr
    prm[4] = -p_vmax[0] * 0.63661977236758134f * si; // kfac
    prm[5] = 1.0f / p_rturn[0];                      // irt
    prm[6] = p_rturn[0];                             // rt
    prm[7] = -LOG2E / p_rd[0];                       // crd
    prm[8] = __log2f(p_i0[0]);                       // li0
    prm[9] = 1.0f / VBINW;                           // invw
    prm[10] = -VBIN0 / VBINW;                        // boff
  }
}

// per-cell math -> (UO = bin coordinate, IO = intensity); independent chain
#define CELL(kk, UO, IO) {                                  \
    const float gz = -993.75f + 12.5f * (float)(kk);        \
    const float ry = fmaf(-si, gz, y1ci);                   \
    const float s2 = fmaf(ry, ry, x12);                     \
    const float rq = sqrtf(s2);                             \
    const float ri = fast_rcp(fmaxf(rq, 1e-30f));           \
    const float at = atan_pos(rq * irt, rt * ri);           \
    const float rs = sqrtf(fmaf(gz, gz, gxy2));             \
    UO = fmaf(kcol * (ri * at), invw, boff);                \
    IO = fast_exp2(fmaf(rs, crd, li0)); }

// run-length CIC merge of one (uu, inten) into (cb, a0, a1); flush on change
#define MERGE(uu, inten) {                                  \
    const int   bi = (int)(uu);                             \
    const float w1 = (inten) * ((uu) - (float)bi);          \
    const float w0 = (inten) - w1;                          \
    if (bi == cb)          { a0 += w0; a1 += w1; }          \
    else if (bi == cb + 1) { unsafeAtomicAdd(&Hc[cb], a0);  \
                             a0 = a1 + w0; a1 = w1; cb = bi; } \
    else { unsafeAtomicAdd(&Hc[cb], a0);                    \
           unsafeAtomicAdd(&Hc[cb + 1], a1);                \
           a0 = w0; a1 = w1; cb = bi; } }

// ---- k2: fused deposit + matvec. SELF=true recomputes prm/G (no-ws path) ----
template<bool SELF>
__global__ __launch_bounds__(256, 7) void fused_kernel(
    const float* __restrict__ p_inc, const float* __restrict__ p_rot,
    const float* __restrict__ p_lb,  const float* __restrict__ p_vs,
    const float* __restrict__ p_vmax, const float* __restrict__ p_rturn,
    const float* __restrict__ p_i0,  const float* __restrict__ p_rd,
    const float* __restrict__ freqs, const float* __restrict__ ws,
    float* __restrict__ out)
{
  __shared__ float Hs[NPIXB * 8 * NBP];   // 32 sub-hists, 20608 B
  __shared__ float H4[NPIXB * NB];        // reduced per-pixel hists, 2560 B

  const int t   = threadIdx.x;
  const int blk = blockIdx.x;                    // 0..1599
  const int p   = blk / (RES / NPIXB);
  const int q0  = (blk - p * (RES / NPIXB)) * NPIXB;

  float ci, si, cr, sr, kfac, irt, rt, crd, li0, invw, boff;
  float c2l = 0.f, norm16 = 0.f, df = 0.f, f0 = 0.f, vshift = 0.f;
  if (SELF) {
    const float inc = p_inc[0], rotv = p_rot[0], sig = p_lb[0];
    si = sinf(inc); ci = cosf(inc); cr = cosf(rotv); sr = sinf(rotv);
    kfac = -p_vmax[0] * 0.63661977236758134f * si;
    rt = p_rturn[0]; irt = 1.0f / rt;
    crd = -LOG2E / p_rd[0]; li0 = __log2f(p_i0[0]);
    invw = 1.0f / VBINW; boff = -VBIN0 / VBINW;
    c2l = -0.5f * LOG2E / (sig * sig);
    norm16 = 0.3989422804014327f / sig * 0.0625f;
    df = (freqs[1] - freqs[0]) * 0.25f;
    f0 = freqs[0] - 1.5f * df;
    vshift = p_vs[0];
  } else {
    const float* prm = ws + PRM_OFF / 4;
    ci = prm[0]; si = prm[1]; cr = prm[2]; sr = prm[3];
    kfac = prm[4]; irt = prm[5]; rt = prm[6]; crd = prm[7];
    li0 = prm[8]; invw = prm[9]; boff = prm[10];
  }

  for (int e = t; e < NPIXB * 8 * NBP; e += 256) Hs[e] = 0.f;
  __syncthreads();

  // ---- deposit: wave = pixel, 4 cols x 16 segments x 10 consecutive z ----
  {
    const int pix = t >> 6;          // 0..3 (wave-uniform)
    const int col = (t >> 4) & 3;    // fine 2x2 pixel
    const int seg = t & 15;          // 10-z segment
    const int i   = 2 * p + (col >> 1);
    const int j   = 2 * (q0 + pix) + (col & 1);
    const float gx = -993.75f + 12.5f * (float)i;
    const float gy = -993.75f + 12.5f * (float)j;
    const float x1 = gx * cr - gy * sr;
    const float y1 = gx * sr + gy * cr;
    const float x12  = x1 * x1;
    const float gxy2 = gx * gx + gy * gy;
    const float y1ci = y1 * ci;
    const float kcol = kfac * x1;
    // seg parity -> different sub-hist: boundary bins of adjacent segments
    // never collide; 8 same-parity segs share one hist via ds_add_f32.
    float* Hc = &Hs[(pix * 8 + col * 2 + (seg & 1)) * NBP];

    const int k0 = seg * 10;
    float U[5], I[5];
    int cb; float a0, a1;
    #pragma unroll
    for (int c = 0; c < 5; ++c) CELL(k0 + c, U[c], I[c])       // batch 1: ILP
    { const int bi = (int)U[0];
      const float w1 = I[0] * (U[0] - (float)bi);
      cb = bi; a0 = I[0] - w1; a1 = w1; }
    #pragma unroll
    for (int c = 1; c < 5; ++c) MERGE(U[c], I[c])
    #pragma unroll
    for (int c = 0; c < 5; ++c) CELL(k0 + 5 + c, U[c], I[c])   // batch 2: ILP
    #pragma unroll
    for (int c = 0; c < 5; ++c) MERGE(U[c], I[c])
    unsafeAtomicAdd(&Hc[cb],     a0);
    unsafeAtomicAdd(&Hc[cb + 1], a1);
  }
  __syncthreads();

  // ---- reduce 8 sub-hists -> per-pixel histogram ----
  for (int e = t; e < NPIXB * NB; e += 256) {
    const int v = e / NB;
    const int b = e - v * NB;
    float s = 0.f;
    #pragma unroll
    for (int c8 = 0; c8 < 8; ++c8) s += Hs[(v * 8 + c8) * NBP + b];
    H4[e] = s;
  }
  __syncthreads();

  // ---- matvec: out[M, pix] = sum_b H4[pix][b] * GT[b][M] ----
  // wave = pixel; lane m = channel (lanes 40..63 idle). H4 read is a
  // broadcast (one LDS address/wave); GT[b*40+m] is a coalesced 160B line
  // (L1-resident, 25.6 KB).
  {
    const int pix = t >> 6;
    const int m   = t & 63;
    if (m < NM) {
      const float* Hv = &H4[pix * NB];
      float acc0 = 0.f, acc1 = 0.f, acc2 = 0.f, acc3 = 0.f;
      if (!SELF) {
        const float* G = ws + GT_OFF / 4 + m;
        #pragma unroll 4
        for (int b = 0; b < NB; b += 4) {
          acc0 = fmaf(Hv[b + 0], G[(b + 0) * NM], acc0);
          acc1 = fmaf(Hv[b + 1], G[(b + 1) * NM], acc1);
          acc2 = fmaf(Hv[b + 2], G[(b + 2) * NM], acc2);
          acc3 = fmaf(Hv[b + 3], G[(b + 3) * NM], acc3);
        }
      } else {
        float vlab[4];
        #pragma unroll
        for (int r = 0; r < 4; ++r) {
          const float ffine = f0 + df * (float)(4 * m + r);
          vlab[r] = C_KMS * (F0GHZ - ffine) / F0GHZ - vshift;
        }
        for (int b = 0; b < NB; ++b) {
          const float vbin = VBIN0 + VBINW * (float)b;
          float g = 0.f;
          #pragma unroll
          for (int r = 0; r < 4; ++r) {
            const float d = vlab[r] - vbin;
            g += fast_exp2(c2l * d * d);
          }
          acc0 = fmaf(Hv[b], g * norm16, acc0);
        }
      }
      out[(size_t)m * NPIXT + p * RES + q0 + pix] =
          (acc0 + acc1) + (acc2 + acc3);
    }
  }
}

extern "C" void kernel_launch(void* const* d_in, const int* in_sizes, int n_in,
                              void* d_out, int out_size, void* d_ws, size_t ws_size,
                              hipStream_t stream) {
  const float* p_inc   = (const float*)d_in[0];
  const float* p_rot   = (const float*)d_in[1];
  const float* p_lb    = (const float*)d_in[2];
  const float* p_vs    = (const float*)d_in[3];
  const float* p_vmax  = (const float*)d_in[4];
  const float* p_rturn = (const float*)d_in[5];
  const float* p_i0    = (const float*)d_in[6];
  const float* p_rd    = (const float*)d_in[7];
  const float* freqs   = (const float*)d_in[8];
  float* out = (float*)d_out;
  float* ws  = (float*)d_ws;

  if (ws_size >= WS_REQ) {
    hipLaunchKernelGGL(gtable_kernel, dim3((NB * NM + 255) / 256), dim3(256),
                       0, stream, p_inc, p_rot, p_lb, p_vs, p_vmax, p_rturn,
                       p_i0, p_rd, freqs, ws);
    hipLaunchKernelGGL((fused_kernel<false>), dim3(NPIXT / NPIXB), dim3(256),
                       0, stream, p_inc, p_rot, p_lb, p_vs, p_vmax, p_rturn,
                       p_i0, p_rd, freqs, ws, out);
  } else {
    hipLaunchKernelGGL((fused_kernel<true>), dim3(NPIXT / NPIXB), dim3(256),
                       0, stream, p_inc, p_rot, p_lb, p_vs, p_vmax, p_rturn,
                       p_i0, p_rd, freqs, ws, out);
  }
}

// Round 8
// 30.696 us; speedup vs baseline: 2.1623x; 1.0367x over previous
//
#include <hip/hip_runtime.h>
#include <hip/hip_bf16.h>
#include <math.h>

// ThickCubeSimulator R7: matvec rebuild (deposit identical to R6 for clean
// attribution).
//  R6 model: matvec issued 160 scalar ds_read_b32 H-broadcasts/wave (~10us
//  chip) and re-read GT from L1 4x redundantly (102KB/block). R7: each wave
//  owns a 40-bin slice for all 4 pixels (GT traffic /4), H read as b128
//  broadcasts (40/wave), partial sums combined via small LDS buffer.
//  Sub-hists 8->4 per pixel (reduce+zero halve; LDS 15.5KB).

#define RES   80
#define NB    160
#define NBP   161
#define NM    40
#define H4P   164        // padded per-pixel H stride (16B-aligned b128 reads)
#define NPIXT (RES*RES)
#define NPIXB 4          // coarse pixels per block
#define C_KMS 299792.458f
#define F0GHZ 230.538f
#define LOG2E 1.44269504088896340736f
#define HPI   1.57079632679489662f
#define VBIN0 -198.75f
#define VBINW 2.5f

// ws layout (bytes): prm floats, then GT[b][M] (NB*NM floats)
#define PRM_OFF 0
#define GT_OFF  128
#define WS_REQ  (GT_OFF + NB * NM * 4)

__device__ __forceinline__ float fast_exp2(float x) {
#if __has_builtin(__builtin_amdgcn_exp2f)
  return __builtin_amdgcn_exp2f(x);
#else
  return exp2f(x);
#endif
}
__device__ __forceinline__ float fast_rcp(float x) {
#if __has_builtin(__builtin_amdgcn_rcpf)
  return __builtin_amdgcn_rcpf(x);
#else
  return 1.0f / x;
#endif
}

// atan(u) for u>=0 via t=min(u,1/u) in [0,1], poly err ~1e-6 rad
__device__ __forceinline__ float atan_pos(float u, float uinv) {
  const float t  = fminf(u, uinv);
  const float t2 = t * t;
  float p = fmaf(t2, -0.0117212f, 0.05265332f);
  p = fmaf(t2, p, -0.11643287f);
  p = fmaf(t2, p, 0.19354346f);
  p = fmaf(t2, p, -0.33262347f);
  p = fmaf(t2, p, 0.99997726f);
  const float a = t * p;
  return (u <= 1.0f) ? a : (HPI - a);
}

// ---- k1: GT table (transposed: GT[b*NM + M]) + params ----
__global__ __launch_bounds__(256) void gtable_kernel(
    const float* __restrict__ p_inc, const float* __restrict__ p_rot,
    const float* __restrict__ p_lb,  const float* __restrict__ p_vs,
    const float* __restrict__ p_vmax, const float* __restrict__ p_rturn,
    const float* __restrict__ p_i0,  const float* __restrict__ p_rd,
    const float* __restrict__ freqs, float* __restrict__ ws)
{
  float* gt = ws + GT_OFF / 4;
  const int e = blockIdx.x * 256 + threadIdx.x;
  if (e < NB * NM) {
    const int b = e / NM;
    const int M = e - b * NM;
    const float sig    = p_lb[0];
    const float vshift = p_vs[0];
    const float fc0    = freqs[0];
    const float fc1    = freqs[1];
    const float c2l    = -0.5f * LOG2E / (sig * sig);
    const float norm16 = 0.3989422804014327f / sig * 0.0625f;
    const float df = (fc1 - fc0) * 0.25f;
    const float f0 = fc0 - 1.5f * df;
    const float vbin = VBIN0 + VBINW * (float)b;
    float s = 0.f;
    #pragma unroll
    for (int r = 0; r < 4; ++r) {
      const float ffine = f0 + df * (float)(4 * M + r);
      const float vlab  = C_KMS * (F0GHZ - ffine) / F0GHZ - vshift;
      const float d = vlab - vbin;
      s += fast_exp2(c2l * d * d);
    }
    gt[e] = s * norm16;
  }
  if (blockIdx.x == 0 && threadIdx.x == 0) {
    const float inc = p_inc[0], rot = p_rot[0];
    const float si = sinf(inc);
    float* prm = ws + PRM_OFF / 4;
    prm[0] = cosf(inc);                              // ci
    prm[1] = si;                                     // si
    prm[2] = cosf(rot);                              // cr
    prm[3] = sinf(rot);                              // sr
    prm[4] = -p_vmax[0] * 0.63661977236758134f * si; // kfac
    prm[5] = 1.0f / p_rturn[0];                      // irt
    prm[6] = p_rturn[0];                             // rt
    prm[7] = -LOG2E / p_rd[0];                       // crd
    prm[8] = __log2f(p_i0[0]);                       // li0
    prm[9] = 1.0f / VBINW;                           // invw
    prm[10] = -VBIN0 / VBINW;                        // boff
  }
}

// per-cell math -> (UO = bin coordinate, IO = intensity); independent chain
#define CELL(kk, UO, IO) {                                  \
    const float gz = -993.75f + 12.5f * (float)(kk);        \
    const float ry = fmaf(-si, gz, y1ci);                   \
    const float s2 = fmaf(ry, ry, x12);                     \
    const float rq = sqrtf(s2);                             \
    const float ri = fast_rcp(fmaxf(rq, 1e-30f));           \
    const float at = atan_pos(rq * irt, rt * ri);           \
    const float rs = sqrtf(fmaf(gz, gz, gxy2));             \
    UO = fmaf(kcol * (ri * at), invw, boff);                \
    IO = fast_exp2(fmaf(rs, crd, li0)); }

// run-length CIC merge of one (uu, inten) into (cb, a0, a1); flush on change
#define MERGE(uu, inten) {                                  \
    const int   bi = (int)(uu);                             \
    const float w1 = (inten) * ((uu) - (float)bi);          \
    const float w0 = (inten) - w1;                          \
    if (bi == cb)          { a0 += w0; a1 += w1; }          \
    else if (bi == cb + 1) { unsafeAtomicAdd(&Hc[cb], a0);  \
                             a0 = a1 + w0; a1 = w1; cb = bi; } \
    else { unsafeAtomicAdd(&Hc[cb], a0);                    \
           unsafeAtomicAdd(&Hc[cb + 1], a1);                \
           a0 = w0; a1 = w1; cb = bi; } }

// ---- k2: fused deposit + matvec. SELF=true recomputes prm/G (no-ws path) ----
template<bool SELF>
__global__ __launch_bounds__(256, 6) void fused_kernel(
    const float* __restrict__ p_inc, const float* __restrict__ p_rot,
    const float* __restrict__ p_lb,  const float* __restrict__ p_vs,
    const float* __restrict__ p_vmax, const float* __restrict__ p_rturn,
    const float* __restrict__ p_i0,  const float* __restrict__ p_rd,
    const float* __restrict__ freqs, const float* __restrict__ ws,
    float* __restrict__ out)
{
  __shared__ float Hs[16 * NBP];                 // 16 sub-hists, 10304 B
  __shared__ __align__(16) float H4[NPIXB * H4P]; // per-pixel hists, 2624 B
  __shared__ float Pp[16 * NM];                  // [w*4+pix][m] partials, 2560 B

  const int t   = threadIdx.x;
  const int blk = blockIdx.x;                    // 0..1599
  const int p   = blk / (RES / NPIXB);
  const int q0  = (blk - p * (RES / NPIXB)) * NPIXB;

  float ci, si, cr, sr, kfac, irt, rt, crd, li0, invw, boff;
  float c2l = 0.f, norm16 = 0.f, df = 0.f, f0 = 0.f, vshift = 0.f;
  if (SELF) {
    const float inc = p_inc[0], rotv = p_rot[0], sig = p_lb[0];
    si = sinf(inc); ci = cosf(inc); cr = cosf(rotv); sr = sinf(rotv);
    kfac = -p_vmax[0] * 0.63661977236758134f * si;
    rt = p_rturn[0]; irt = 1.0f / rt;
    crd = -LOG2E / p_rd[0]; li0 = __log2f(p_i0[0]);
    invw = 1.0f / VBINW; boff = -VBIN0 / VBINW;
    c2l = -0.5f * LOG2E / (sig * sig);
    norm16 = 0.3989422804014327f / sig * 0.0625f;
    df = (freqs[1] - freqs[0]) * 0.25f;
    f0 = freqs[0] - 1.5f * df;
    vshift = p_vs[0];
  } else {
    const float* prm = ws + PRM_OFF / 4;
    ci = prm[0]; si = prm[1]; cr = prm[2]; sr = prm[3];
    kfac = prm[4]; irt = prm[5]; rt = prm[6]; crd = prm[7];
    li0 = prm[8]; invw = prm[9]; boff = prm[10];
  }

  for (int e = t; e < 16 * NBP; e += 256) Hs[e] = 0.f;
  __syncthreads();

  // ---- deposit: wave = pixel, 4 cols x 16 segments x 10 consecutive z ----
  {
    const int pix = t >> 6;          // 0..3 (wave-uniform)
    const int col = (t >> 4) & 3;    // fine 2x2 pixel
    const int seg = t & 15;          // 10-z segment
    const int i   = 2 * p + (col >> 1);
    const int j   = 2 * (q0 + pix) + (col & 1);
    const float gx = -993.75f + 12.5f * (float)i;
    const float gy = -993.75f + 12.5f * (float)j;
    const float x1 = gx * cr - gy * sr;
    const float y1 = gx * sr + gy * cr;
    const float x12  = x1 * x1;
    const float gxy2 = gx * gx + gy * gy;
    const float y1ci = y1 * ci;
    const float kcol = kfac * x1;
    float* Hc = &Hs[(pix * 4 + col) * NBP];

    const int k0 = seg * 10;
    float U[5], I[5];
    int cb; float a0, a1;
    #pragma unroll
    for (int c = 0; c < 5; ++c) CELL(k0 + c, U[c], I[c])       // batch 1: ILP
    { const int bi = (int)U[0];
      const float w1 = I[0] * (U[0] - (float)bi);
      cb = bi; a0 = I[0] - w1; a1 = w1; }
    #pragma unroll
    for (int c = 1; c < 5; ++c) MERGE(U[c], I[c])
    #pragma unroll
    for (int c = 0; c < 5; ++c) CELL(k0 + 5 + c, U[c], I[c])   // batch 2: ILP
    #pragma unroll
    for (int c = 0; c < 5; ++c) MERGE(U[c], I[c])
    unsafeAtomicAdd(&Hc[cb],     a0);
    unsafeAtomicAdd(&Hc[cb + 1], a1);
  }
  __syncthreads();

  // ---- reduce 4 sub-hists -> per-pixel histogram (padded stride) ----
  for (int e = t; e < NPIXB * NB; e += 256) {
    const int v = e / NB;
    const int b = e - v * NB;
    H4[v * H4P + b] = (Hs[(v * 4 + 0) * NBP + b] + Hs[(v * 4 + 1) * NBP + b])
                    + (Hs[(v * 4 + 2) * NBP + b] + Hs[(v * 4 + 3) * NBP + b]);
  }
  __syncthreads();

  // ---- matvec ----
  if (!SELF) {
    // wave w owns bin slice [40w, 40w+40) for ALL 4 pixels; lane = channel m.
    // GT[b][M] reads stay coalesced (160B lines, L1-resident; 25.6KB/block
    // total = 4x less than R6). H read as b128 broadcasts (40/wave).
    const int w = t >> 6;
    const int l = t & 63;
    float acc[NPIXB] = {0.f, 0.f, 0.f, 0.f};
    if (l < NM) {
      const float* G = ws + GT_OFF / 4 + l;   // + b*NM per bin
      const int b0w = w * 40;
      #pragma unroll
      for (int c4 = 0; c4 < 10; ++c4) {
        const int b0 = b0w + c4 * 4;
        const float g0 = G[(b0 + 0) * NM];
        const float g1 = G[(b0 + 1) * NM];
        const float g2 = G[(b0 + 2) * NM];
        const float g3 = G[(b0 + 3) * NM];
        #pragma unroll
        for (int pix = 0; pix < NPIXB; ++pix) {
          const float4 h = *(const float4*)&H4[pix * H4P + b0];
          acc[pix] = fmaf(h.x, g0, fmaf(h.y, g1,
                     fmaf(h.z, g2, fmaf(h.w, g3, acc[pix]))));
        }
      }
      #pragma unroll
      for (int pix = 0; pix < NPIXB; ++pix)
        Pp[(w * NPIXB + pix) * NM + l] = acc[pix];
    }
    __syncthreads();
    if (t < NPIXB * NM) {
      const int m   = t >> 2;
      const int pix = t & 3;
      const float s = (Pp[(0 * NPIXB + pix) * NM + m] +
                       Pp[(1 * NPIXB + pix) * NM + m]) +
                      (Pp[(2 * NPIXB + pix) * NM + m] +
                       Pp[(3 * NPIXB + pix) * NM + m]);
      out[(size_t)m * NPIXT + p * RES + q0 + pix] = s;
    }
  } else {
    // fallback: on-the-fly G, whole-range per wave (R6 structure)
    const int pix = t >> 6;
    const int m   = t & 63;
    if (m < NM) {
      const float* Hv = &H4[pix * H4P];
      float vlab[4];
      #pragma unroll
      for (int r = 0; r < 4; ++r) {
        const float ffine = f0 + df * (float)(4 * m + r);
        vlab[r] = C_KMS * (F0GHZ - ffine) / F0GHZ - vshift;
      }
      float acc = 0.f;
      for (int b = 0; b < NB; ++b) {
        const float vbin = VBIN0 + VBINW * (float)b;
        float g = 0.f;
        #pragma unroll
        for (int r = 0; r < 4; ++r) {
          const float d = vlab[r] - vbin;
          g += fast_exp2(c2l * d * d);
        }
        acc = fmaf(Hv[b], g * norm16, acc);
      }
      out[(size_t)m * NPIXT + p * RES + q0 + pix] = acc;
    }
  }
}

extern "C" void kernel_launch(void* const* d_in, const int* in_sizes, int n_in,
                              void* d_out, int out_size, void* d_ws, size_t ws_size,
                              hipStream_t stream) {
  const float* p_inc   = (const float*)d_in[0];
  const float* p_rot   = (const float*)d_in[1];
  const float* p_lb    = (const float*)d_in[2];
  const float* p_vs    = (const float*)d_in[3];
  const float* p_vmax  = (const float*)d_in[4];
  const float* p_rturn = (const float*)d_in[5];
  const float* p_i0    = (const float*)d_in[6];
  const float* p_rd    = (const float*)d_in[7];
  const float* freqs   = (const float*)d_in[8];
  float* out = (float*)d_out;
  float* ws  = (float*)d_ws;

  if (ws_size >= WS_REQ) {
    hipLaunchKernelGGL(gtable_kernel, dim3((NB * NM + 255) / 256), dim3(256),
                       0, stream, p_inc, p_rot, p_lb, p_vs, p_vmax, p_rturn,
                       p_i0, p_rd, freqs, ws);
    hipLaunchKernelGGL((fused_kernel<false>), dim3(NPIXT / NPIXB), dim3(256),
                       0, stream, p_inc, p_rot, p_lb, p_vs, p_vmax, p_rturn,
                       p_i0, p_rd, freqs, ws, out);
  } else {
    hipLaunchKernelGGL((fused_kernel<true>), dim3(NPIXT / NPIXB), dim3(256),
                       0, stream, p_inc, p_rot, p_lb, p_vs, p_vmax, p_rturn,
                       p_i0, p_rd, freqs, ws, out);
  }
}